// Round 6
// baseline (213.799 us; speedup 1.0000x reference)
//
#include <hip/hip_runtime.h>
#include <hip/hip_fp16.h>
#include <hip/hip_cooperative_groups.h>

namespace cg = cooperative_groups;

#define N_NODES   100000
#define N_CLASSES 16
#define N_EDGES   3200000

// ---- fused cooperative kernel ----
#define GRID_F    255
#define B_F       1024
#define R_DYN     3
#define NPR_DYN   33334                 // nodes per range
#define DYN_BYTES (NPR_DYN * 4)         // 133336 B dynamic LDS
#define S_DYN     85                    // slices (GRID_F / R_DYN)
#define EPS_DYN   37648                 // edges per slice (mult of 4; 85*37648 >= E)
#define KE        8                     // edges per thread-chunk, edge phase

// ---- static-LDS degree (fallback path) ----
#define R_ST      8
#define NPR_ST    12500
#define S_ST      64
#define EPS_ST    50000
#define B_DEG     1024

// ===================== fp8 e4m3 helpers =====================

__device__ __forceinline__ unsigned f2fp8(float f) {
    unsigned u = __float_as_uint(f);
    unsigned s = (u >> 24) & 0x80u;
    float g = fabsf(f) * 0x1p-120f;
    unsigned gu = __float_as_uint(g);
    gu += 0x7FFFFu + ((gu >> 20) & 1u);       // RNE at bit 20
    unsigned mag = gu >> 20;
    if (mag > 0x7Eu) mag = 0x7Eu;             // clamp to 448
    return s | mag;
}

__device__ __forceinline__ float fp82f(unsigned b) {
    unsigned u = ((b & 0x80u) << 24) | ((b & 0x7Fu) << 20);
    return __uint_as_float(u) * 0x1p120f;
}

__device__ __forceinline__ float ssd4(unsigned a, unsigned b) {
    float s = 0.0f;
#pragma unroll
    for (int i = 0; i < 4; ++i) {
        float va = fp82f((a >> (8 * i)) & 0xFFu);
        float vb = fp82f((b >> (8 * i)) & 0xFFu);
        float d = va - vb;
        s += d * d;
    }
    return s;
}

// ===================== fused cooperative kernel =====================

__global__ __launch_bounds__(B_F) void lap_fused(
        const int* __restrict__ rows, const int* __restrict__ cols,
        const float* __restrict__ w, const float* __restrict__ y,
        __half* __restrict__ shadows, unsigned char* __restrict__ yhat,
        float* __restrict__ out) {
    extern __shared__ float hist[];
    cg::grid_group grid = cg::this_grid();

    // ---------- Phase A: degree histograms -> fp16 shadows ----------
    {
        const int b   = blockIdx.x;
        const int r   = b % R_DYN;
        const int s   = b / R_DYN;
        const int lo  = r * NPR_DYN;
        const int hi  = (lo + NPR_DYN < N_NODES) ? lo + NPR_DYN : N_NODES;
        const int cnt = hi - lo;

        if (b == 0 && threadIdx.x == 0) out[0] = 0.0f;

        for (int i = threadIdx.x; i < cnt; i += B_F) hist[i] = 0.0f;
        __syncthreads();

        const int base = s * EPS_DYN;
        for (int g = threadIdx.x; g < EPS_DYN / 4; g += B_F) {
            const int e = base + g * 4;
            if (e >= N_EDGES) continue;       // tail slice guard (E%4==0)
            int4   r4 = *(const int4*)(rows + e);
            float4 w4 = *(const float4*)(w + e);
            int t;
            t = r4.x - lo; if ((unsigned)t < (unsigned)cnt) atomicAdd(&hist[t], w4.x);
            t = r4.y - lo; if ((unsigned)t < (unsigned)cnt) atomicAdd(&hist[t], w4.y);
            t = r4.z - lo; if ((unsigned)t < (unsigned)cnt) atomicAdd(&hist[t], w4.z);
            t = r4.w - lo; if ((unsigned)t < (unsigned)cnt) atomicAdd(&hist[t], w4.w);
        }
        __syncthreads();

        __half* dst = shadows + (size_t)s * N_NODES + lo;
        for (int i = threadIdx.x; i < cnt; i += B_F) dst[i] = __float2half(hist[i]);
    }

    grid.sync();

    // ---------- Phase B: reduce shadows -> rsqrt -> fp8 yhat ----------
    {
        const int nb = (N_NODES + GRID_F - 1) / GRID_F;   // 393
        const int n  = blockIdx.x * nb + threadIdx.x;
        if (threadIdx.x < nb && n < N_NODES) {
            float deg = 0.0f;
            for (int s = 0; s < S_DYN; ++s)
                deg += __half2float(shadows[(size_t)s * N_NODES + n]);
            const float inv = rsqrtf(deg);
            const float4* yr = (const float4*)(y + (size_t)n * N_CLASSES);
            uint4 o;
            unsigned* op = (unsigned*)&o;
#pragma unroll
            for (int j = 0; j < 4; ++j) {
                float4 v = yr[j];
                op[j] =  f2fp8(v.x * inv)
                      | (f2fp8(v.y * inv) << 8)
                      | (f2fp8(v.z * inv) << 16)
                      | (f2fp8(v.w * inv) << 24);
            }
            *(uint4*)(yhat + (size_t)n * N_CLASSES) = o;
        }
    }

    grid.sync();

    // ---------- Phase C: fp8 edge pass, fused mean ----------
    {
        const int  tid     = blockIdx.x * B_F + threadIdx.x;
        const long stride  = (long)GRID_F * B_F * KE;
        float local = 0.0f;
        for (long e0 = (long)tid * KE; e0 < N_EDGES; e0 += stride) {
            int4   ra = *(const int4*)(rows + e0);
            int4   rb = *(const int4*)(rows + e0 + 4);
            int4   ca = *(const int4*)(cols + e0);
            int4   cb = *(const int4*)(cols + e0 + 4);
            float4 wa = *(const float4*)(w + e0);
            float4 wb = *(const float4*)(w + e0 + 4);

            const int ri[KE] = {ra.x, ra.y, ra.z, ra.w, rb.x, rb.y, rb.z, rb.w};
            const int ci[KE] = {ca.x, ca.y, ca.z, ca.w, cb.x, cb.y, cb.z, cb.w};
            const float wv[KE] = {wa.x, wa.y, wa.z, wa.w, wb.x, wb.y, wb.z, wb.w};

            uint4 A[KE], B[KE];
#pragma unroll
            for (int k = 0; k < KE; ++k) {
                A[k] = *(const uint4*)(yhat + (size_t)ri[k] * N_CLASSES);
                B[k] = *(const uint4*)(yhat + (size_t)ci[k] * N_CLASSES);
            }
#pragma unroll
            for (int k = 0; k < KE; ++k) {
                float s = ssd4(A[k].x, B[k].x) + ssd4(A[k].y, B[k].y)
                        + ssd4(A[k].z, B[k].z) + ssd4(A[k].w, B[k].w);
                local += wv[k] * sqrtf(s);
            }
        }
#pragma unroll
        for (int off = 32; off > 0; off >>= 1) local += __shfl_down(local, off, 64);
        __syncthreads();                       // hist reuse as reduce scratch
        const int lane = threadIdx.x & 63;
        const int wid  = threadIdx.x >> 6;     // 0..15
        if (lane == 0) hist[wid] = local;
        __syncthreads();
        if (threadIdx.x == 0) {
            float t = 0.0f;
#pragma unroll
            for (int i = 0; i < B_F / 64; ++i) t += hist[i];
            atomicAdd(out, t * (1.0f / (float)N_EDGES));
        }
    }
}

// ===================== fallback path kernels (R4) =====================

__global__ __launch_bounds__(B_DEG) void lap_degree_static(
        const int* __restrict__ rows, const float* __restrict__ w,
        __half* __restrict__ shadows) {
    __shared__ float hist[NPR_ST];
    const int r  = blockIdx.x & (R_ST - 1);
    const int s  = blockIdx.x >> 3;
    const int lo = r * NPR_ST;

    for (int i = threadIdx.x; i < NPR_ST; i += B_DEG) hist[i] = 0.0f;
    __syncthreads();

    const int base = s * EPS_ST;
    for (int g = threadIdx.x; g < EPS_ST / 4; g += B_DEG) {
        const int e = base + g * 4;
        int4   r4 = *(const int4*)(rows + e);
        float4 w4 = *(const float4*)(w + e);
        int t;
        t = r4.x - lo; if ((unsigned)t < (unsigned)NPR_ST) atomicAdd(&hist[t], w4.x);
        t = r4.y - lo; if ((unsigned)t < (unsigned)NPR_ST) atomicAdd(&hist[t], w4.y);
        t = r4.z - lo; if ((unsigned)t < (unsigned)NPR_ST) atomicAdd(&hist[t], w4.z);
        t = r4.w - lo; if ((unsigned)t < (unsigned)NPR_ST) atomicAdd(&hist[t], w4.w);
    }
    __syncthreads();

    __half* dst = shadows + (size_t)s * N_NODES + lo;
    for (int i = threadIdx.x; i < NPR_ST; i += B_DEG) dst[i] = __float2half(hist[i]);
}

__global__ void lap_yhat_super(const __half* __restrict__ shadows,
                               const float* __restrict__ y,
                               unsigned char* __restrict__ yhat, int S) {
    const int n = blockIdx.x * blockDim.x + threadIdx.x;
    if (n >= N_NODES) return;
    float deg = 0.0f;
    for (int s = 0; s < S; ++s) deg += __half2float(shadows[(size_t)s * N_NODES + n]);
    const float inv = rsqrtf(deg);
    const float4* yr = (const float4*)(y + (size_t)n * N_CLASSES);
    uint4 o;
    unsigned* op = (unsigned*)&o;
#pragma unroll
    for (int j = 0; j < 4; ++j) {
        float4 v = yr[j];
        op[j] =  f2fp8(v.x * inv)
              | (f2fp8(v.y * inv) << 8)
              | (f2fp8(v.z * inv) << 16)
              | (f2fp8(v.w * inv) << 24);
    }
    *(uint4*)(yhat + (size_t)n * N_CLASSES) = o;
}

__global__ void lap_edge_fp8(const int* __restrict__ rows,
                             const int* __restrict__ cols,
                             const float* __restrict__ w,
                             const unsigned char* __restrict__ yhat,
                             float* __restrict__ out) {
    const int tid = blockIdx.x * blockDim.x + threadIdx.x;
    const long e0 = (long)tid * KE;
    float local = 0.0f;
    if (e0 < N_EDGES) {
        int4   ra = *(const int4*)(rows + e0);
        int4   rb = *(const int4*)(rows + e0 + 4);
        int4   ca = *(const int4*)(cols + e0);
        int4   cb = *(const int4*)(cols + e0 + 4);
        float4 wa = *(const float4*)(w + e0);
        float4 wb = *(const float4*)(w + e0 + 4);

        const int ri[KE] = {ra.x, ra.y, ra.z, ra.w, rb.x, rb.y, rb.z, rb.w};
        const int ci[KE] = {ca.x, ca.y, ca.z, ca.w, cb.x, cb.y, cb.z, cb.w};
        const float wv[KE] = {wa.x, wa.y, wa.z, wa.w, wb.x, wb.y, wb.z, wb.w};

        uint4 A[KE], B[KE];
#pragma unroll
        for (int k = 0; k < KE; ++k) {
            A[k] = *(const uint4*)(yhat + (size_t)ri[k] * N_CLASSES);
            B[k] = *(const uint4*)(yhat + (size_t)ci[k] * N_CLASSES);
        }
#pragma unroll
        for (int k = 0; k < KE; ++k) {
            float s = ssd4(A[k].x, B[k].x) + ssd4(A[k].y, B[k].y)
                    + ssd4(A[k].z, B[k].z) + ssd4(A[k].w, B[k].w);
            local += wv[k] * sqrtf(s);
        }
    }
#pragma unroll
    for (int off = 32; off > 0; off >>= 1) local += __shfl_down(local, off, 64);
    __shared__ float sm[4];
    const int lane = threadIdx.x & 63;
    const int wid  = threadIdx.x >> 6;
    if (lane == 0) sm[wid] = local;
    __syncthreads();
    if (threadIdx.x == 0)
        atomicAdd(out, (sm[0] + sm[1] + sm[2] + sm[3]) * (1.0f / (float)N_EDGES));
}

// low fallback (tiny ws)
__global__ void lap_degree_kernel(const int* __restrict__ rows,
                                  const float* __restrict__ w,
                                  float* __restrict__ degree) {
    int i = blockIdx.x * blockDim.x + threadIdx.x;
    if (i < N_EDGES) atomicAdd(&degree[rows[i]], w[i]);
}

__global__ void lap_invd_kernel(const float* __restrict__ degree,
                                float* __restrict__ invd) {
    int i = blockIdx.x * blockDim.x + threadIdx.x;
    if (i < N_NODES) invd[i] = rsqrtf(degree[i]);
}

__global__ void lap_edge_kernel(const int* __restrict__ rows,
                                const int* __restrict__ cols,
                                const float* __restrict__ w,
                                const float* __restrict__ y,
                                const float* __restrict__ invd,
                                float* __restrict__ out) {
    int i = blockIdx.x * blockDim.x + threadIdx.x;
    float local = 0.0f;
    if (i < N_EDGES) {
        int r = rows[i], c = cols[i];
        float dr = invd[r], dc = invd[c];
        const float4* yr = (const float4*)(y + (size_t)r * N_CLASSES);
        const float4* yc = (const float4*)(y + (size_t)c * N_CLASSES);
        float s = 0.0f;
#pragma unroll
        for (int j = 0; j < N_CLASSES / 4; ++j) {
            float4 a = yr[j], b = yc[j];
            float d0 = a.x * dr - b.x * dc;
            float d1 = a.y * dr - b.y * dc;
            float d2 = a.z * dr - b.z * dc;
            float d3 = a.w * dr - b.w * dc;
            s += d0 * d0 + d1 * d1 + d2 * d2 + d3 * d3;
        }
        local = w[i] * sqrtf(s);
    }
#pragma unroll
    for (int off = 32; off > 0; off >>= 1) local += __shfl_down(local, off, 64);
    __shared__ float sm[4];
    int lane = threadIdx.x & 63, wid = threadIdx.x >> 6;
    if (lane == 0) sm[wid] = local;
    __syncthreads();
    if (threadIdx.x == 0)
        atomicAdd(out, (sm[0] + sm[1] + sm[2] + sm[3]) * (1.0f / (float)N_EDGES));
}

// ===================== launch =====================

extern "C" void kernel_launch(void* const* d_in, const int* in_sizes, int n_in,
                              void* d_out, int out_size, void* d_ws, size_t ws_size,
                              hipStream_t stream) {
    const int*   edge_index = (const int*)d_in[0];   // [rows | cols]
    const float* w          = (const float*)d_in[1];
    const float* y          = (const float*)d_in[2];
    float*       out        = (float*)d_out;

    const int* rows = edge_index;
    const int* cols = edge_index + N_EDGES;
    const int  B = 256;

    // shared layout: [shadows: S_DYN*N halves][yhat: N*16 fp8 bytes]
    const size_t sh_bytes   = (size_t)S_DYN * N_NODES * sizeof(__half);   // 17 MB
    const size_t need_super = sh_bytes + (size_t)N_NODES * N_CLASSES;

    if (ws_size >= need_super) {
        __half*        shadows = (__half*)d_ws;
        unsigned char* yhat    = (unsigned char*)d_ws + sh_bytes;

        hipError_t ok = hipFuncSetAttribute(
            reinterpret_cast<const void*>(lap_fused),
            hipFuncAttributeMaxDynamicSharedMemorySize, DYN_BYTES);

        if (ok == hipSuccess) {
            void* args[] = {(void*)&rows, (void*)&cols, (void*)&w, (void*)&y,
                            (void*)&shadows, (void*)&yhat, (void*)&out};
            ok = hipLaunchCooperativeKernel(
                reinterpret_cast<const void*>(lap_fused),
                dim3(GRID_F), dim3(B_F), args, DYN_BYTES, stream);
        }
        if (ok != hipSuccess) {
            // fallback: multi-kernel path (static-LDS degree, S=64)
            hipMemsetAsync(d_out, 0, sizeof(float), stream);
            lap_degree_static<<<R_ST * S_ST, B_DEG, 0, stream>>>(rows, w, shadows);
            lap_yhat_super<<<(N_NODES + B - 1) / B, B, 0, stream>>>(shadows, y, yhat, S_ST);
            lap_edge_fp8<<<(N_EDGES / KE + B - 1) / B, B, 0, stream>>>(rows, cols, w, yhat, out);
        }
    } else {
        float* degree = (float*)d_ws;
        float* invd   = degree + N_NODES;
        hipMemsetAsync(d_out, 0, sizeof(float), stream);
        hipMemsetAsync(d_ws, 0, (size_t)N_NODES * sizeof(float), stream);
        lap_degree_kernel<<<(N_EDGES + B - 1) / B, B, 0, stream>>>(rows, w, degree);
        lap_invd_kernel<<<(N_NODES + B - 1) / B, B, 0, stream>>>(degree, invd);
        lap_edge_kernel<<<(N_EDGES + B - 1) / B, B, 0, stream>>>(rows, cols, w, y, invd, out);
    }
}

// Round 7
// 160.457 us; speedup vs baseline: 1.3324x; 1.3324x over previous
//
#include <hip/hip_runtime.h>
#include <hip/hip_fp16.h>

#define N_NODES   100000
#define N_CLASSES 16
#define N_EDGES   3200000

// ---- degree: R=5 ranges, 80 KB dynamic LDS, 2 blocks/CU ----
#define R5        5
#define NPR5      20000                 // nodes per range
#define DYN5      (NPR5 * 4)            // 80000 B dynamic LDS
#define S5        102                   // slices -> 510 blocks
#define EPS5      31376                 // edges per slice (mult of 4; 102*31376 >= E)

// ---- degree fallback: static 50 KB, R=8 ----
#define R_ST      8
#define NPR_ST    12500
#define S_ST      64
#define EPS_ST    50000

#define B_DEG     1024
#define KE        8                     // edges per thread, edge pass

// ===================== fp8 e4m3 helpers =====================
// Manual encode produces OCP e4m3fn bit patterns (bias 7, max 448),
// so the HW decoder v_cvt_pk_f32_fp8 reads them exactly.

__device__ __forceinline__ unsigned f2fp8(float f) {
    unsigned u = __float_as_uint(f);
    unsigned s = (u >> 24) & 0x80u;
    float g = fabsf(f) * 0x1p-120f;
    unsigned gu = __float_as_uint(g);
    gu += 0x7FFFFu + ((gu >> 20) & 1u);       // RNE at bit 20
    unsigned mag = gu >> 20;
    if (mag > 0x7Eu) mag = 0x7Eu;             // clamp to 448
    return s | mag;
}

__device__ __forceinline__ float fp82f(unsigned b) {
    unsigned u = ((b & 0x80u) << 24) | ((b & 0x7Fu) << 20);
    return __uint_as_float(u) * 0x1p120f;
}

#if defined(__has_builtin)
#if __has_builtin(__builtin_amdgcn_cvt_pk_f32_fp8)
#define HAVE_HW_FP8 1
#endif
#endif

#ifdef HAVE_HW_FP8
typedef float v2f __attribute__((ext_vector_type(2)));
__device__ __forceinline__ float ssd4(unsigned a, unsigned b) {
    v2f a0 = __builtin_amdgcn_cvt_pk_f32_fp8((int)a, false);
    v2f a1 = __builtin_amdgcn_cvt_pk_f32_fp8((int)a, true);
    v2f b0 = __builtin_amdgcn_cvt_pk_f32_fp8((int)b, false);
    v2f b1 = __builtin_amdgcn_cvt_pk_f32_fp8((int)b, true);
    float d0 = a0.x - b0.x;
    float d1 = a0.y - b0.y;
    float d2 = a1.x - b1.x;
    float d3 = a1.y - b1.y;
    return d0 * d0 + d1 * d1 + d2 * d2 + d3 * d3;
}
#else
__device__ __forceinline__ float ssd4(unsigned a, unsigned b) {
    float s = 0.0f;
#pragma unroll
    for (int i = 0; i < 4; ++i) {
        float va = fp82f((a >> (8 * i)) & 0xFFu);
        float vb = fp82f((b >> (8 * i)) & 0xFFu);
        float d = va - vb;
        s += d * d;
    }
    return s;
}
#endif

// ===================== degree: R=5, dynamic 80 KB LDS =====================

__global__ __launch_bounds__(B_DEG, 8) void lap_degree_r5(
        const int* __restrict__ rows, const float* __restrict__ w,
        __half* __restrict__ shadows, float* __restrict__ out) {
    extern __shared__ float hist[];
    const int b  = blockIdx.x;
    const int r  = b % R5;
    const int s  = b / R5;
    const int lo = r * NPR5;

    if (b == 0 && threadIdx.x == 0) out[0] = 0.0f;

    for (int i = threadIdx.x; i < NPR5; i += B_DEG) hist[i] = 0.0f;
    __syncthreads();

    const int base = s * EPS5;
    for (int g = threadIdx.x; g < EPS5 / 4; g += B_DEG) {
        const int e = base + g * 4;
        if (e >= N_EDGES) continue;          // tail slice guard (E % 4 == 0)
        int4   r4 = *(const int4*)(rows + e);
        float4 w4 = *(const float4*)(w + e);
        int t;
        t = r4.x - lo; if ((unsigned)t < (unsigned)NPR5) atomicAdd(&hist[t], w4.x);
        t = r4.y - lo; if ((unsigned)t < (unsigned)NPR5) atomicAdd(&hist[t], w4.y);
        t = r4.z - lo; if ((unsigned)t < (unsigned)NPR5) atomicAdd(&hist[t], w4.z);
        t = r4.w - lo; if ((unsigned)t < (unsigned)NPR5) atomicAdd(&hist[t], w4.w);
    }
    __syncthreads();

    __half* dst = shadows + (size_t)s * N_NODES + lo;
    for (int i = threadIdx.x; i < NPR5; i += B_DEG) dst[i] = __float2half(hist[i]);
}

// ===================== degree fallback: static 50 KB, R=8 =====================

__global__ __launch_bounds__(B_DEG) void lap_degree_static(
        const int* __restrict__ rows, const float* __restrict__ w,
        __half* __restrict__ shadows, float* __restrict__ out) {
    __shared__ float hist[NPR_ST];
    const int r  = blockIdx.x & (R_ST - 1);
    const int s  = blockIdx.x >> 3;
    const int lo = r * NPR_ST;

    if (blockIdx.x == 0 && threadIdx.x == 0) out[0] = 0.0f;

    for (int i = threadIdx.x; i < NPR_ST; i += B_DEG) hist[i] = 0.0f;
    __syncthreads();

    const int base = s * EPS_ST;
    for (int g = threadIdx.x; g < EPS_ST / 4; g += B_DEG) {
        const int e = base + g * 4;
        int4   r4 = *(const int4*)(rows + e);
        float4 w4 = *(const float4*)(w + e);
        int t;
        t = r4.x - lo; if ((unsigned)t < (unsigned)NPR_ST) atomicAdd(&hist[t], w4.x);
        t = r4.y - lo; if ((unsigned)t < (unsigned)NPR_ST) atomicAdd(&hist[t], w4.y);
        t = r4.z - lo; if ((unsigned)t < (unsigned)NPR_ST) atomicAdd(&hist[t], w4.z);
        t = r4.w - lo; if ((unsigned)t < (unsigned)NPR_ST) atomicAdd(&hist[t], w4.w);
    }
    __syncthreads();

    __half* dst = shadows + (size_t)s * N_NODES + lo;
    for (int i = threadIdx.x; i < NPR_ST; i += B_DEG) dst[i] = __float2half(hist[i]);
}

// ===================== reduce shadows -> rsqrt -> fp8 yhat =====================

__global__ void lap_yhat(const __half* __restrict__ shadows,
                         const float* __restrict__ y,
                         unsigned char* __restrict__ yhat, int S) {
    const int n = blockIdx.x * blockDim.x + threadIdx.x;
    if (n >= N_NODES) return;
    float deg = 0.0f;
    for (int s = 0; s < S; ++s) deg += __half2float(shadows[(size_t)s * N_NODES + n]);
    const float inv = rsqrtf(deg);

    const float4* yr = (const float4*)(y + (size_t)n * N_CLASSES);
    uint4 o;
    unsigned* op = (unsigned*)&o;
#pragma unroll
    for (int j = 0; j < 4; ++j) {
        float4 v = yr[j];
        op[j] =  f2fp8(v.x * inv)
              | (f2fp8(v.y * inv) << 8)
              | (f2fp8(v.z * inv) << 16)
              | (f2fp8(v.w * inv) << 24);
    }
    *(uint4*)(yhat + (size_t)n * N_CLASSES) = o;
}

// ===================== edge pass: fp8 HW decode, fused mean =====================

__global__ void lap_edge_fp8(const int* __restrict__ rows,
                             const int* __restrict__ cols,
                             const float* __restrict__ w,
                             const unsigned char* __restrict__ yhat,
                             float* __restrict__ out) {
    const int tid = blockIdx.x * blockDim.x + threadIdx.x;
    const long e0 = (long)tid * KE;
    float local = 0.0f;
    if (e0 < N_EDGES) {
        int4   ra = *(const int4*)(rows + e0);
        int4   rb = *(const int4*)(rows + e0 + 4);
        int4   ca = *(const int4*)(cols + e0);
        int4   cb = *(const int4*)(cols + e0 + 4);
        float4 wa = *(const float4*)(w + e0);
        float4 wb = *(const float4*)(w + e0 + 4);

        const int ri[KE] = {ra.x, ra.y, ra.z, ra.w, rb.x, rb.y, rb.z, rb.w};
        const int ci[KE] = {ca.x, ca.y, ca.z, ca.w, cb.x, cb.y, cb.z, cb.w};
        const float wv[KE] = {wa.x, wa.y, wa.z, wa.w, wb.x, wb.y, wb.z, wb.w};

        uint4 A[KE], B[KE];
#pragma unroll
        for (int k = 0; k < KE; ++k) {
            A[k] = *(const uint4*)(yhat + (size_t)ri[k] * N_CLASSES);
            B[k] = *(const uint4*)(yhat + (size_t)ci[k] * N_CLASSES);
        }
#pragma unroll
        for (int k = 0; k < KE; ++k) {
            float s = ssd4(A[k].x, B[k].x) + ssd4(A[k].y, B[k].y)
                    + ssd4(A[k].z, B[k].z) + ssd4(A[k].w, B[k].w);
            local += wv[k] * sqrtf(s);
        }
    }
#pragma unroll
    for (int off = 32; off > 0; off >>= 1) local += __shfl_down(local, off, 64);
    __shared__ float sm[4];
    const int lane = threadIdx.x & 63;
    const int wid  = threadIdx.x >> 6;
    if (lane == 0) sm[wid] = local;
    __syncthreads();
    if (threadIdx.x == 0)
        atomicAdd(out, (sm[0] + sm[1] + sm[2] + sm[3]) * (1.0f / (float)N_EDGES));
}

// ===================== low fallback (tiny ws) =====================

__global__ void lap_degree_kernel(const int* __restrict__ rows,
                                  const float* __restrict__ w,
                                  float* __restrict__ degree) {
    int i = blockIdx.x * blockDim.x + threadIdx.x;
    if (i < N_EDGES) atomicAdd(&degree[rows[i]], w[i]);
}

__global__ void lap_invd_kernel(const float* __restrict__ degree,
                                float* __restrict__ invd) {
    int i = blockIdx.x * blockDim.x + threadIdx.x;
    if (i < N_NODES) invd[i] = rsqrtf(degree[i]);
}

__global__ void lap_edge_kernel(const int* __restrict__ rows,
                                const int* __restrict__ cols,
                                const float* __restrict__ w,
                                const float* __restrict__ y,
                                const float* __restrict__ invd,
                                float* __restrict__ out) {
    int i = blockIdx.x * blockDim.x + threadIdx.x;
    float local = 0.0f;
    if (i < N_EDGES) {
        int r = rows[i], c = cols[i];
        float dr = invd[r], dc = invd[c];
        const float4* yr = (const float4*)(y + (size_t)r * N_CLASSES);
        const float4* yc = (const float4*)(y + (size_t)c * N_CLASSES);
        float s = 0.0f;
#pragma unroll
        for (int j = 0; j < N_CLASSES / 4; ++j) {
            float4 a = yr[j], b = yc[j];
            float d0 = a.x * dr - b.x * dc;
            float d1 = a.y * dr - b.y * dc;
            float d2 = a.z * dr - b.z * dc;
            float d3 = a.w * dr - b.w * dc;
            s += d0 * d0 + d1 * d1 + d2 * d2 + d3 * d3;
        }
        local = w[i] * sqrtf(s);
    }
#pragma unroll
    for (int off = 32; off > 0; off >>= 1) local += __shfl_down(local, off, 64);
    __shared__ float sm[4];
    int lane = threadIdx.x & 63, wid = threadIdx.x >> 6;
    if (lane == 0) sm[wid] = local;
    __syncthreads();
    if (threadIdx.x == 0)
        atomicAdd(out, (sm[0] + sm[1] + sm[2] + sm[3]) * (1.0f / (float)N_EDGES));
}

// ===================== launch =====================

extern "C" void kernel_launch(void* const* d_in, const int* in_sizes, int n_in,
                              void* d_out, int out_size, void* d_ws, size_t ws_size,
                              hipStream_t stream) {
    const int*   edge_index = (const int*)d_in[0];   // [rows | cols]
    const float* w          = (const float*)d_in[1];
    const float* y          = (const float*)d_in[2];
    float*       out        = (float*)d_out;

    const int* rows = edge_index;
    const int* cols = edge_index + N_EDGES;
    const int  B = 256;

    // layout: [shadows: S5*N halves (20.4 MB)][yhat: N*16 fp8 bytes]
    const size_t sh_bytes   = (size_t)S5 * N_NODES * sizeof(__half);
    const size_t need_super = sh_bytes + (size_t)N_NODES * N_CLASSES;

    const int edge_blocks = (N_EDGES / KE + B - 1) / B;   // 1563

    if (ws_size >= need_super) {
        __half*        shadows = (__half*)d_ws;
        unsigned char* yhat    = (unsigned char*)d_ws + sh_bytes;

        hipError_t ok = hipFuncSetAttribute(
            reinterpret_cast<const void*>(lap_degree_r5),
            hipFuncAttributeMaxDynamicSharedMemorySize, DYN5);

        if (ok == hipSuccess) {
            lap_degree_r5<<<R5 * S5, B_DEG, DYN5, stream>>>(rows, w, shadows, out);
            lap_yhat<<<(N_NODES + B - 1) / B, B, 0, stream>>>(shadows, y, yhat, S5);
        } else {
            lap_degree_static<<<R_ST * S_ST, B_DEG, 0, stream>>>(rows, w, shadows, out);
            lap_yhat<<<(N_NODES + B - 1) / B, B, 0, stream>>>(shadows, y, yhat, S_ST);
        }
        lap_edge_fp8<<<edge_blocks, B, 0, stream>>>(rows, cols, w, yhat, out);
    } else {
        float* degree = (float*)d_ws;
        float* invd   = degree + N_NODES;
        hipMemsetAsync(d_out, 0, sizeof(float), stream);
        hipMemsetAsync(d_ws, 0, (size_t)N_NODES * sizeof(float), stream);
        lap_degree_kernel<<<(N_EDGES + B - 1) / B, B, 0, stream>>>(rows, w, degree);
        lap_invd_kernel<<<(N_NODES + B - 1) / B, B, 0, stream>>>(degree, invd);
        lap_edge_kernel<<<(N_EDGES + B - 1) / B, B, 0, stream>>>(rows, cols, w, y, invd, out);
    }
}